// Round 17
// baseline (76.371 us; speedup 1.0000x reference)
//
#include <hip/hip_runtime.h>
#include <hip/hip_bf16.h>
#include <math.h>

#define NB    4
#define NC    128
#define NPIX  3136      // 56*56
#define CHW   401408    // 128*3136
#define KVP   3968      // padded K/V image: 62 rows x 64 stride
#define STS   19        // conv transpose-buffer row stride (odd => bank-clean)

// ---------- DPP wave64 sum (VALU pipe, no DS) ------------------------------
template <int CTRL, int RM>
__device__ __forceinline__ float dpp_mov(float x, float old) {
    return __int_as_float(__builtin_amdgcn_update_dpp(
        __float_as_int(old), __float_as_int(x), CTRL, RM, 0xf, false));
}
__device__ __forceinline__ float wave_sum(float x) {
    x = x + dpp_mov<0x111, 0xf>(x, 0.f);   // row_shr:1
    x = x + dpp_mov<0x112, 0xf>(x, 0.f);   // row_shr:2
    x = x + dpp_mov<0x114, 0xf>(x, 0.f);   // row_shr:4
    x = x + dpp_mov<0x118, 0xf>(x, 0.f);   // row_shr:8
    x = x + dpp_mov<0x142, 0xa>(x, 0.f);   // row_bcast:15 -> rows 1,3
    x = x + dpp_mov<0x143, 0xc>(x, 0.f);   // row_bcast:31 -> rows 2,3
    return __int_as_float(__builtin_amdgcn_readlane(__float_as_int(x), 63));
}

// ---------------- prep: halo bias-fill (stride-64 padded) + weights + rb ---
__global__ __launch_bounds__(256) void prep_kernel(
    const float* __restrict__ qw, const float* __restrict__ kw,
    const float* __restrict__ vw,
    const float* __restrict__ kb, const float* __restrict__ vb,
    const float* __restrict__ rel_h, const float* __restrict__ rel_w,
    float* __restrict__ kpad, float* __restrict__ vpad,
    float* __restrict__ w4q, float* __restrict__ w4k, float* __restrict__ w4v,
    float* __restrict__ rb)
{
    int idx = blockIdx.x * 256 + threadIdx.x;
    {   // halo: 708 positions per image, 512 images (grid == 362496 threads)
        int img = idx / 708;
        int hl = idx - img * 708;
        int p;
        if (hl < 186) {                    // rows 0..2, cols 0..61
            int r = hl / 62;
            p = r * 64 + (hl - r * 62);
        } else if (hl < 372) {             // rows 59..61, cols 0..61
            int j = hl - 186;
            int r = j / 62;
            p = (59 + r) * 64 + (j - r * 62);
        } else {                           // rows 3..58, cols {0,1,2,59,60,61}
            int j = hl - 372;
            int r = j / 6, cc = j - r * 6;
            p = (r + 3) * 64 + (cc < 3 ? cc : cc + 56);
        }
        int ch = img & 127;
        size_t o = (size_t)img * KVP + p;
        kpad[o] = kb[ch];
        vpad[o] = vb[ch];
    }
    if (idx < 3 * 16384) {
        int m = idx >> 14;
        int r = idx & 16383;          // dst-linear: ((c4*128 + o)*4 + cc)
        int cc = r & 3;
        int t = r >> 2;
        int o = t & 127;
        int c4 = t >> 7;
        const float* src = (m == 0) ? qw : (m == 1) ? kw : vw;
        float* dst = (m == 0) ? w4q : (m == 1) ? w4k : w4v;
        dst[r] = src[o * 128 + c4 * 4 + cc];
    }
    if (idx < 14) {
        const float* src = (idx < 7) ? rel_h : rel_w;
        int off = (idx < 7) ? idx : idx - 7;
        float s = 0.f;
        for (int c = 0; c < 64; ++c) s += src[c * 7 + off];
        rb[idx] = s;
    }
}

// ---------------- conv: fused 1x1 convs Q,K,V (fp32, r13 verbatim) ---------
// lane=o compute (coalesced W4 loads, depth-1 prefetch, batched x reads);
// stride-19 LDS transpose; lane=pixel stores: q unpadded, K/V padded-64.
__global__ __launch_bounds__(256) void conv_kernel(
    const float* __restrict__ x,
    const float* __restrict__ w4q, const float* __restrict__ w4k,
    const float* __restrict__ w4v,
    const float* __restrict__ qb, const float* __restrict__ kb,
    const float* __restrict__ vb,
    float* __restrict__ q, float* __restrict__ kpad, float* __restrict__ vpad)
{
    __shared__ float sx[128 * 16];       // [c][pix] 8KB
    __shared__ float st[3 * 128 * STS];  // q/k/v transpose planes, 28.5KB
    int bid = blockIdx.x;
    int tile = bid % 196;
    int b = bid / 196;
    int pix0 = tile * 16;
    const float* xb = x + b * CHW + pix0;

    for (int i = threadIdx.x; i < 512; i += 256) {
        int c = i >> 2, p4 = (i & 3) * 4;
        *(float4*)(sx + c * 16 + p4) = *(const float4*)(xb + c * NPIX + p4);
    }
    __syncthreads();

    int lane = threadIdx.x & 63;
    int wave = threadIdx.x >> 6;
    int o = wave * 32 + (lane & 31);
    int ph = (lane >> 5) * 8;
    const float4* Wq = (const float4*)w4q + o;
    const float4* Wk = (const float4*)w4k + o;
    const float4* Wv = (const float4*)w4v + o;

    float4 wqc = Wq[0], wkc = Wk[0], wvc = Wv[0];   // pipeline head
    float aq[8] = {}, ak[8] = {}, av[8] = {};
    #pragma unroll 1
    for (int c4 = 0; c4 < 32; ++c4) {
        float4 xs[8];
        #pragma unroll
        for (int cc = 0; cc < 4; ++cc) {
            xs[2 * cc]     = *(const float4*)(sx + (c4 * 4 + cc) * 16 + ph);
            xs[2 * cc + 1] = *(const float4*)(sx + (c4 * 4 + cc) * 16 + ph + 4);
        }
        float4 wq4 = wqc, wk4 = wkc, wv4 = wvc;
        if (c4 < 31) {   // prefetch next iter's weights (covered by FMAs)
            wqc = Wq[(c4 + 1) * 128];
            wkc = Wk[(c4 + 1) * 128];
            wvc = Wv[(c4 + 1) * 128];
        }
        float wqr[4] = {wq4.x, wq4.y, wq4.z, wq4.w};
        float wkr[4] = {wk4.x, wk4.y, wk4.z, wk4.w};
        float wvr[4] = {wv4.x, wv4.y, wv4.z, wv4.w};
        #pragma unroll
        for (int cc = 0; cc < 4; ++cc) {
            float4 xa = xs[2 * cc], xc = xs[2 * cc + 1];
            float xv[8] = {xa.x, xa.y, xa.z, xa.w, xc.x, xc.y, xc.z, xc.w};
            #pragma unroll
            for (int p = 0; p < 8; ++p) {
                aq[p] += wqr[cc] * xv[p];
                ak[p] += wkr[cc] * xv[p];
                av[p] += wvr[cc] * xv[p];
            }
        }
    }
    float bq = qb[o], bk = kb[o], bv = vb[o];
    float* wrq = st + o * STS + ph;
    float* wrk = st + 128 * STS + o * STS + ph;
    float* wrv = st + 2 * 128 * STS + o * STS + ph;
    #pragma unroll
    for (int p = 0; p < 8; ++p) {
        wrq[p] = aq[p] + bq;
        wrk[p] = ak[p] + bk;
        wrv[p] = av[p] + bv;
    }
    __syncthreads();

    int pix = threadIdx.x & 15;
    int o8 = (threadIdx.x >> 4) * 8;
    int pp = pix0 + pix;
    int yy = pp / 56, xx = pp - yy * 56;
    int po = (yy + 3) * 64 + xx + 3;                    // padded dest offset
    float* qd = q + b * CHW + pix0 + pix;
    float* kd = kpad + (size_t)b * 128 * KVP + po;
    float* vd = vpad + (size_t)b * 128 * KVP + po;
    #pragma unroll
    for (int i = 0; i < 8; ++i) {
        int r = o8 + i;
        qd[r * NPIX] = st[r * STS + pix];
        kd[(size_t)r * KVP] = st[128 * STS + r * STS + pix];
        vd[(size_t)r * KVP] = st[2 * 128 * STS + r * STS + pix];
    }
}

// ---------------- attn: NO K/V staging — read padded global (L2-resident) --
// r14 arithmetic verbatim (fp32, shift-softmax, q one-group prefetch); K/V
// come straight from kpad/vpad. LDS holds only the per-wave w buffer.
__global__ __launch_bounds__(256) void attn_kernel(
    const float* __restrict__ q, const float* __restrict__ kpad,
    const float* __restrict__ vpad,
    const float* __restrict__ rb, float* __restrict__ out)
{
    __shared__ float sW[4 * 64];
    int bid = blockIdx.x;
    int qpart = bid & 3;
    int bc = bid >> 2;
    int qr0 = 14 * qpart;
    const float* qc = q + bc * NPIX + 784 * qpart;
    const float* kq = kpad + (size_t)bc * KVP + qr0 * 64;  // quarter row base
    const float* vq = vpad + (size_t)bc * KVP + qr0 * 64;
    float* oc = out + bc * NPIX + 784 * qpart;

    int lane = threadIdx.x & 63;
    int wave = threadIdx.x >> 6;
    int k2 = min(lane, 48);
    int di = k2 / 7, dj = k2 - di * 7;
    float rbias = rb[di] + rb[7 + dj];
    const float* kwin = kq + di * 64 + dj;     // per-lane window base
    int t16 = lane & 15, p = lane >> 4;
    float* sWw = sW + wave * 64;

    // uniform rbias extrema (once per block)
    float rhM = rb[0], rhm = rb[0];
    #pragma unroll
    for (int i = 1; i < 7; ++i) { rhM = fmaxf(rhM, rb[i]); rhm = fminf(rhm, rb[i]); }
    float rwM = rb[7], rwm = rb[7];
    #pragma unroll
    for (int i = 8; i < 14; ++i) { rwM = fmaxf(rwM, rb[i]); rwm = fminf(rwm, rb[i]); }
    float rdMax = rbias - (rhM + rwM);   // <= 0 per lane
    float rdMin = rbias - (rhm + rwm);   // >= 0 per lane

    // prefetch first group's q
    int ul0 = wave * 16;               // LOCAL pixel index within quarter
    int y0 = 0, x0 = ul0;
    float4 p0 = *(const float4*)(qc + ul0);
    float4 p1 = *(const float4*)(qc + ul0 + 4);
    float4 p2 = *(const float4*)(qc + ul0 + 8);
    float4 p3 = *(const float4*)(qc + ul0 + 12);

    for (int gl = wave; gl < 49; gl += 4) {
        // --- QK (2 chains) + qs (tree), straight from prefetch regs ------
        float qs = (((p0.x + p0.y) + (p0.z + p0.w)) + ((p1.x + p1.y) + (p1.z + p1.w)))
                 + (((p2.x + p2.y) + (p2.z + p2.w)) + ((p3.x + p3.y) + (p3.z + p3.w)));
        const float* kp = kwin + y0 * 64 + x0;
        int d2 = (x0 == 48) ? 16 : 8;              // row-wrap continuation
        const float* kp2 = kp + d2;
        float a0, a1;
        a0  = p0.x * kp[0];   a1  = p0.y * kp[1];
        a0 += p0.z * kp[2];   a1 += p0.w * kp[3];
        a0 += p1.x * kp[4];   a1 += p1.y * kp[5];
        a0 += p1.z * kp[6];   a1 += p1.w * kp[7];
        a0 += p2.x * kp2[0];  a1 += p2.y * kp2[1];
        a0 += p2.z * kp2[2];  a1 += p2.w * kp2[3];
        a0 += p3.x * kp2[4];  a1 += p3.y * kp2[5];
        a0 += p3.z * kp2[6];  a1 += p3.w * kp2[7];
        float acc = a0 + a1;

        // --- reload q regs for group gl+4 (after last use) ---------------
        if (gl + 4 < 49) {
            int un = ul0 + 64;
            p0 = *(const float4*)(qc + un);
            p1 = *(const float4*)(qc + un + 4);
            p2 = *(const float4*)(qc + un + 8);
            p3 = *(const float4*)(qc + un + 12);
        }

        // --- shift-softmax: u = qs*rbsel (uniform) -> no max reduce ------
        float rd = (qs > 0.f) ? rdMax : rdMin;
        float ex = fmaf(qs, rd, acc);
        float e = (lane < 49) ? __expf(ex) : 0.f;
        float sS = wave_sum(e);
        float wgt = e * __builtin_amdgcn_rcpf(sS);
        sWw[lane] = wgt;                           // lanes 49..63 write 0

        // --- PV: lane = (t, ki-row-pair p); V from global ----------------
        int u = ul0 + t16;
        int yt = u / 56;
        int xt = u - yt * 56;
        const float* vb0 = vq + (yt + 2 * p) * 64 + xt;
        const float* wbase = sWw + p * 14;
        float o0 = 0.f, o1 = 0.f;
        #pragma unroll
        for (int j = 0; j < 7; ++j) o0 += wbase[j] * vb0[j];
        #pragma unroll
        for (int j = 0; j < 7; ++j) o1 += wbase[7 + j] * vb0[64 + j];
        float oacc = o0 + o1;
        oacc += __shfl_xor(oacc, 16);
        oacc += __shfl_xor(oacc, 32);
        if (lane < 16) oc[ul0 + lane] = oacc;

        // advance local coords: ul0 += 64 => y0 += 1, x0 += 8 (with carry)
        ul0 += 64;
        x0 += 8; y0 += 1;
        if (x0 >= 56) { x0 -= 56; ++y0; }
    }
}

extern "C" void kernel_launch(void* const* d_in, const int* in_sizes, int n_in,
                              void* d_out, int out_size, void* d_ws, size_t ws_size,
                              hipStream_t stream) {
    const float* x     = (const float*)d_in[0];
    const float* qw    = (const float*)d_in[1];
    const float* qb    = (const float*)d_in[2];
    const float* kw    = (const float*)d_in[3];
    const float* kb    = (const float*)d_in[4];
    const float* vw    = (const float*)d_in[5];
    const float* vb    = (const float*)d_in[6];
    const float* rel_h = (const float*)d_in[7];
    const float* rel_w = (const float*)d_in[8];
    float* out = (float*)d_out;

    float* ws   = (float*)d_ws;
    float* kpad = ws;                    // 512*3968 = 2031616
    float* vpad = kpad + 2031616;        // 2031616 (benign x0 overrun -> qbuf)
    float* qbuf = vpad + 2031616;        // 1605632
    float* w4q  = qbuf + 1605632;        // 16384
    float* w4k  = w4q + 16384;
    float* w4v  = w4k + 16384;
    float* rb   = w4v + 16384;           // 16

    prep_kernel<<<1416, 256, 0, stream>>>(qw, kw, vw, kb, vb, rel_h, rel_w,
                                          kpad, vpad, w4q, w4k, w4v, rb);
    conv_kernel<<<784, 256, 0, stream>>>(x, w4q, w4k, w4v, qb, kb, vb,
                                         qbuf, kpad, vpad);
    attn_kernel<<<2048, 256, 0, stream>>>(qbuf, kpad, vpad, rb, out);
}